// Round 3
// baseline (1340.217 us; speedup 1.0000x reference)
//
#include <hip/hip_runtime.h>
#include <hip/hip_bf16.h>
#include <cstdint>

typedef _Float16 f16;
typedef f16 f16x4 __attribute__((ext_vector_type(4)));
typedef f16 f16x8 __attribute__((ext_vector_type(8)));
typedef float f32x4 __attribute__((ext_vector_type(4)));

static constexpr int Hh = 64;   // hidden
static constexpr int Tt = 30;   // seq len
static constexpr int Ii = 9;    // input features
static constexpr int BT = 64;   // batch tile per block
static constexpr int HP = 68;   // padded h-row stride (halves)
static constexpr int XP = 20;   // padded x-row stride (halves)

__device__ __forceinline__ float bf2f(unsigned short u){
  return __uint_as_float(((unsigned int)u) << 16);
}
// fast activations: v_rcp_f32 (~1 ulp) instead of IEEE divide (~12 VALU ops)
__device__ __forceinline__ float sigm(float x){
  float e = __expf(-x);                       // v_mul + v_exp
  return __builtin_amdgcn_rcpf(1.0f + e);     // x->-inf: e=inf -> rcp(inf)=0  (no NaN)
}
__device__ __forceinline__ float tanh_(float x){
  float e = __expf(-2.0f*x);                  // x->-inf: e=inf -> rcp=0 -> -1; x->+inf: e=0 -> 1
  return __builtin_fmaf(2.0f, __builtin_amdgcn_rcpf(1.0f + e), -1.0f);
}

template<bool BF16>
__device__ __forceinline__ float ldv(const void* p, long i){
  if constexpr (BF16) return bf2f(((const unsigned short*)p)[i]);
  else                return ((const float*)p)[i];
}

__device__ __forceinline__ f16x8 ld8lds(const f16* p){
  f16x4 lo = *(const f16x4*)p;        // ds_read_b64
  f16x4 hi = *(const f16x4*)(p + 4);  // ds_read_b64
  f16x8 r;
  r[0]=lo[0]; r[1]=lo[1]; r[2]=lo[2]; r[3]=lo[3];
  r[4]=hi[0]; r[5]=hi[1]; r[6]=hi[2]; r[7]=hi[3];
  return r;
}

// Detect whether tensors are bf16 (reinterpreting bf16 pairs as fp32 gives |v| ~ 2^125)
__global__ void detect_dtype(const void* x, int* flag){
  if (threadIdx.x == 0 && blockIdx.x == 0){
    const float* f = (const float*)x;
    int big = 0;
    for (int i = 0; i < 64; ++i){
      float v = f[i];
      if (!(fabsf(v) < 1e10f)) big = 1;   // NaN/Inf/huge -> bf16 data
    }
    *flag = big;
  }
}

// MFMA 16x16x32 f16 mapping:
//   A: m = lane&15, k = (lane>>4)*8 + j   (8 contiguous halves)
//   B: n = lane&15, k = (lane>>4)*8 + j   (= row n of original W[256][K], contiguous k)
//   C/D: n = lane&15, m = (lane>>4)*4 + reg
template<bool BF16>
__device__ void lstm_body(const void* __restrict__ x,
                          const void* __restrict__ Wih0, const void* __restrict__ Whh0,
                          const void* __restrict__ bih0, const void* __restrict__ bhh0,
                          const void* __restrict__ Wih1, const void* __restrict__ Whh1,
                          const void* __restrict__ bih1, const void* __restrict__ bhh1,
                          const void* __restrict__ gmma, const void* __restrict__ beta,
                          void* __restrict__ out,
                          f16* h0s, f16* h1s, f16* xs)
{
  const int tid  = threadIdx.x;
  const int w    = tid >> 6;      // wave 0..3
  const int lane = tid & 63;
  const int c    = lane & 15;
  const int q    = lane >> 4;
  const long base = (long)blockIdx.x * BT;

  // ---- zero-init state buffers (buf 0) and x staging (both bufs incl. pad) ----
  for (int i = tid; i < BT*HP; i += 256){ h0s[i] = (f16)0.f; h1s[i] = (f16)0.f; }
  for (int i = tid; i < 2*BT*XP; i += 256) xs[i] = (f16)0.f;
  __syncthreads();

  // ---- load weight B-fragments into registers (once) ----
  f16x8 Bhh0v[4][2], Bih1v[4][2], Bhh1v[4][2], Bih0v[4];
  float b0g[4], b1g[4];
  for (int g = 0; g < 4; ++g){
    const int n = 64*g + 16*w + c;
    for (int kt = 0; kt < 2; ++kt){
      const long off = (long)n*64 + kt*32 + q*8;
      for (int j = 0; j < 8; ++j){
        Bhh0v[g][kt][j] = (f16)ldv<BF16>(Whh0, off + j);
        Bih1v[g][kt][j] = (f16)ldv<BF16>(Wih1, off + j);
        Bhh1v[g][kt][j] = (f16)ldv<BF16>(Whh1, off + j);
      }
    }
    f16x8 bi = {};                       // zero-filled: k>=9 contributes 0
    if (q == 0){ for (int j = 0; j < 8; ++j) bi[j] = (f16)ldv<BF16>(Wih0, (long)n*9 + j); }
    else if (q == 1){ bi[0] = (f16)ldv<BF16>(Wih0, (long)n*9 + 8); }
    Bih0v[g] = bi;
    b0g[g] = ldv<BF16>(bih0, n) + ldv<BF16>(bhh0, n);
    b1g[g] = ldv<BF16>(bih1, n) + ldv<BF16>(bhh1, n);
  }

  // ---- x staging bookkeeping (all /9 hoisted out of the T-loop) ----
  int  xs_off[3]; long xg[3]; bool xv[3];
  for (int it = 0; it < 3; ++it){
    int e = tid + 256*it;
    xv[it] = (e < BT*Ii);
    int s = e / 9, i = e - s*9;
    if (!xv[it]){ s = 0; i = 0; }
    xs_off[it] = s*XP + i;
    xg[it] = (base + s)*(long)(Tt*Ii) + i;   // index of x[s][0][i]
  }
  // stage t=0 into xs buf 0; advance indices to t=1
  for (int it = 0; it < 3; ++it){
    if (xv[it]) xs[xs_off[it]] = (f16)ldv<BF16>(x, xg[it]);
    xg[it] += Ii;
  }

  float c0[4][4] = {};   // cell state L0: sample mt*16+4q+r, unit 16w+c
  float c1[4][4] = {};
  float hreg[4][4];      // final-step h1 (fp32) kept in regs until after last barrier
  float xpv[3];
  __syncthreads();

  for (int t = 0; t < Tt; ++t){
    const int rb = t & 1, wb = rb ^ 1;
    f16* h0r = h0s + rb*BT*HP; f16* h0w = h0s + wb*BT*HP;
    f16* h1r = h1s + rb*BT*HP; f16* h1w = h1s + wb*BT*HP;
    f16* xr  = xs  + rb*BT*XP; f16* xw  = xs  + wb*BT*XP;

    // prefetch x(t+1) into regs (hide HBM latency behind MFMA)
    const bool pf = (t + 1 < Tt);
    if (pf){
      for (int it = 0; it < 3; ++it){
        if (xv[it]) xpv[it] = ldv<BF16>(x, xg[it]);
        xg[it] += Ii;
      }
    }

    // ---- Phase A: layer0 gates = h0 @ Whh0^T + xpad @ Wih0^T + b0 ----
    f16x8 ah[4][2], ax[4];
    for (int mt = 0; mt < 4; ++mt){
      const f16* hp = &h0r[(mt*16 + c)*HP];
      ah[mt][0] = ld8lds(hp + q*8);
      ah[mt][1] = ld8lds(hp + 32 + q*8);
      f16x8 a = {};
      if (q < 2) a = ld8lds(&xr[(mt*16 + c)*XP + q*8]);  // k>=16 lanes supply zeros
      ax[mt] = a;
    }
    f32x4 acc[4][4];
    for (int mt = 0; mt < 4; ++mt)
      for (int g = 0; g < 4; ++g){
        f32x4 a = { b0g[g], b0g[g], b0g[g], b0g[g] };
        a = __builtin_amdgcn_mfma_f32_16x16x32_f16(ah[mt][0], Bhh0v[g][0], a, 0,0,0);
        a = __builtin_amdgcn_mfma_f32_16x16x32_f16(ah[mt][1], Bhh0v[g][1], a, 0,0,0);
        a = __builtin_amdgcn_mfma_f32_16x16x32_f16(ax[mt],    Bih0v[g],    a, 0,0,0);
        acc[mt][g] = a;
      }

    // ---- Phase B: layer0 cell update, h0_new -> LDS ----
    for (int mt = 0; mt < 4; ++mt)
      for (int r = 0; r < 4; ++r){
        float ig = sigm(acc[mt][0][r]);
        float fg = sigm(acc[mt][1][r]);
        float gg = tanh_(acc[mt][2][r]);
        float og = sigm(acc[mt][3][r]);
        float cn = __builtin_fmaf(fg, c0[mt][r], ig*gg);
        c0[mt][r] = cn;
        h0w[(mt*16 + 4*q + r)*HP + 16*w + c] = (f16)(og*tanh_(cn));
      }
    __syncthreads();

    // ---- Phase C: layer1 gates = h0_new @ Wih1^T + h1 @ Whh1^T + b1 ----
    f16x8 a0[4][2], a1[4][2];
    for (int mt = 0; mt < 4; ++mt){
      const f16* p0 = &h0w[(mt*16 + c)*HP];
      a0[mt][0] = ld8lds(p0 + q*8);
      a0[mt][1] = ld8lds(p0 + 32 + q*8);
      const f16* p1 = &h1r[(mt*16 + c)*HP];
      a1[mt][0] = ld8lds(p1 + q*8);
      a1[mt][1] = ld8lds(p1 + 32 + q*8);
    }
    for (int mt = 0; mt < 4; ++mt)
      for (int g = 0; g < 4; ++g){
        f32x4 a = { b1g[g], b1g[g], b1g[g], b1g[g] };
        a = __builtin_amdgcn_mfma_f32_16x16x32_f16(a0[mt][0], Bih1v[g][0], a, 0,0,0);
        a = __builtin_amdgcn_mfma_f32_16x16x32_f16(a0[mt][1], Bih1v[g][1], a, 0,0,0);
        a = __builtin_amdgcn_mfma_f32_16x16x32_f16(a1[mt][0], Bhh1v[g][0], a, 0,0,0);
        a = __builtin_amdgcn_mfma_f32_16x16x32_f16(a1[mt][1], Bhh1v[g][1], a, 0,0,0);
        acc[mt][g] = a;
      }

    // ---- Phase D: layer1 cell update, h1_new -> LDS ----
    for (int mt = 0; mt < 4; ++mt)
      for (int r = 0; r < 4; ++r){
        float ig = sigm(acc[mt][0][r]);
        float fg = sigm(acc[mt][1][r]);
        float gg = tanh_(acc[mt][2][r]);
        float og = sigm(acc[mt][3][r]);
        float cn = __builtin_fmaf(fg, c1[mt][r], ig*gg);
        c1[mt][r] = cn;
        float hh = og*tanh_(cn);
        c1[mt][r] = cn;
        hreg[mt][r] = hh;                 // kept; only final step's value survives the loop
        h1w[(mt*16 + 4*q + r)*HP + 16*w + c] = (f16)hh;
      }
    if (pf){
      for (int it = 0; it < 3; ++it)
        if (xv[it]) xw[xs_off[it]] = (f16)xpv[it];
    }
    __syncthreads();
  }

  // ---- LayerNorm over final h1 (fp32). h0s/h1s are dead now -> alias scratch. ----
  float* hfin = (float*)h0s;            // BT x (Hh+1) fp32 = 16640 B <= 17408 B
  float* mus  = (float*)h1s;
  float* rss  = mus + BT;
  for (int mt = 0; mt < 4; ++mt)
    for (int r = 0; r < 4; ++r)
      hfin[(mt*16 + 4*q + r)*(Hh+1) + 16*w + c] = hreg[mt][r];
  __syncthreads();

  if (tid < BT){
    float s = 0.f, s2 = 0.f;
    for (int u = 0; u < Hh; ++u){ float v = hfin[tid*(Hh+1) + u]; s += v; s2 += v*v; }
    float m   = s  * (1.0f/Hh);
    float var = s2 * (1.0f/Hh) - m*m;     // biased var, matches jnp.var
    mus[tid] = m;
    rss[tid] = rsqrtf(var + 1e-5f);
  }
  __syncthreads();
  for (int itx = 0; itx < (BT*Hh)/256; ++itx){
    int idx = itx*256 + tid;
    int s = idx >> 6, u = idx & 63;
    float v = (hfin[s*(Hh+1) + u] - mus[s]) * rss[s];
    v = __builtin_fmaf(v, ldv<BF16>(gmma, u), ldv<BF16>(beta, u));
    long o = base*Hh + idx;
    if constexpr (BF16) ((__hip_bfloat16*)out)[o] = __float2bfloat16(v);
    else                ((float*)out)[o] = v;
  }
}

__global__ __launch_bounds__(256, 3) void lstm_fused(
    const void* __restrict__ x,
    const void* __restrict__ Wih0, const void* __restrict__ Whh0,
    const void* __restrict__ bih0, const void* __restrict__ bhh0,
    const void* __restrict__ Wih1, const void* __restrict__ Whh1,
    const void* __restrict__ bih1, const void* __restrict__ bhh1,
    const void* __restrict__ gmma, const void* __restrict__ beta,
    void* __restrict__ out, const int* __restrict__ flag)
{
  __shared__ __align__(16) f16 h0s[2*BT*HP];   // 17408 B (reused as fp32 hfin after loop)
  __shared__ __align__(16) f16 h1s[2*BT*HP];   // 17408 B (reused as mus/rss after loop)
  __shared__ __align__(16) f16 xs[2*BT*XP];    //  5120 B        -> total ~40 KB

  if (*flag)
    lstm_body<true >(x, Wih0, Whh0, bih0, bhh0, Wih1, Whh1, bih1, bhh1, gmma, beta,
                     out, h0s, h1s, xs);
  else
    lstm_body<false>(x, Wih0, Whh0, bih0, bhh0, Wih1, Whh1, bih1, bhh1, gmma, beta,
                     out, h0s, h1s, xs);
}

extern "C" void kernel_launch(void* const* d_in, const int* in_sizes, int n_in,
                              void* d_out, int out_size, void* d_ws, size_t ws_size,
                              hipStream_t stream) {
  const int B = in_sizes[0] / (Tt * Ii);   // 65536
  int* flag = (int*)d_ws;
  hipLaunchKernelGGL(detect_dtype, dim3(1), dim3(64), 0, stream, d_in[0], flag);
  hipLaunchKernelGGL(lstm_fused, dim3(B / BT), dim3(256), 0, stream,
                     d_in[0], d_in[1], d_in[2], d_in[3], d_in[4], d_in[5], d_in[6],
                     d_in[7], d_in[8], d_in[9], d_in[10], d_out, (const int*)flag);
}

// Round 4
// 639.751 us; speedup vs baseline: 2.0949x; 2.0949x over previous
//
#include <hip/hip_runtime.h>
#include <hip/hip_bf16.h>
#include <cstdint>

typedef _Float16 f16;
typedef f16 f16x4 __attribute__((ext_vector_type(4)));
typedef f16 f16x8 __attribute__((ext_vector_type(8)));
typedef float f32x4 __attribute__((ext_vector_type(4)));

static constexpr int Hh = 64;   // hidden
static constexpr int Tt = 30;   // seq len
static constexpr int Ii = 9;    // input features
static constexpr int BT = 64;   // batch tile per block
static constexpr int HP = 68;   // padded h-row stride (halves)
static constexpr int XP = 20;   // padded x-row stride (halves)

__device__ __forceinline__ float bf2f(unsigned short u){
  return __uint_as_float(((unsigned int)u) << 16);
}
// fast activations: v_rcp_f32 (~1 ulp) instead of IEEE divide (~12 VALU ops)
__device__ __forceinline__ float sigm(float x){
  float e = __expf(-x);                       // v_mul + v_exp
  return __builtin_amdgcn_rcpf(1.0f + e);     // x->-inf: e=inf -> rcp(inf)=0  (no NaN)
}
__device__ __forceinline__ float tanh_(float x){
  float e = __expf(-2.0f*x);                  // x->-inf: e=inf -> rcp=0 -> -1; x->+inf: e=0 -> 1
  return __builtin_fmaf(2.0f, __builtin_amdgcn_rcpf(1.0f + e), -1.0f);
}

template<bool BF16>
__device__ __forceinline__ float ldv(const void* p, long i){
  if constexpr (BF16) return bf2f(((const unsigned short*)p)[i]);
  else                return ((const float*)p)[i];
}

__device__ __forceinline__ f16x8 ld8lds(const f16* p){
  f16x4 lo = *(const f16x4*)p;        // ds_read_b64
  f16x4 hi = *(const f16x4*)(p + 4);  // ds_read_b64
  f16x8 r;
  r[0]=lo[0]; r[1]=lo[1]; r[2]=lo[2]; r[3]=lo[3];
  r[4]=hi[0]; r[5]=hi[1]; r[6]=hi[2]; r[7]=hi[3];
  return r;
}

// Detect whether tensors are bf16 (reinterpreting bf16 pairs as fp32 gives |v| ~ 2^125)
__global__ void detect_dtype(const void* x, int* flag){
  if (threadIdx.x == 0 && blockIdx.x == 0){
    const float* f = (const float*)x;
    int big = 0;
    for (int i = 0; i < 64; ++i){
      float v = f[i];
      if (!(fabsf(v) < 1e10f)) big = 1;   // NaN/Inf/huge -> bf16 data
    }
    *flag = big;
  }
}

// MFMA 16x16x32 f16 mapping:
//   A: m = lane&15, k = (lane>>4)*8 + j   (8 contiguous halves)
//   B: n = lane&15, k = (lane>>4)*8 + j   (= row n of original W[256][K], contiguous k)
//   C/D: n = lane&15, m = (lane>>4)*4 + reg
template<bool BF16>
__device__ void lstm_body(const void* __restrict__ x,
                          const void* __restrict__ Wih0, const void* __restrict__ Whh0,
                          const void* __restrict__ bih0, const void* __restrict__ bhh0,
                          const void* __restrict__ Wih1, const void* __restrict__ Whh1,
                          const void* __restrict__ bih1, const void* __restrict__ bhh1,
                          const void* __restrict__ gmma, const void* __restrict__ beta,
                          void* __restrict__ out,
                          f16* h0s, f16* h1s, f16* xs)
{
  const int tid  = threadIdx.x;
  const int w    = tid >> 6;      // wave 0..3
  const int lane = tid & 63;
  const int c    = lane & 15;
  const int q    = lane >> 4;
  const long base = (long)blockIdx.x * BT;

  // ---- zero-init state buffers (buf 0) and x staging (both bufs incl. pad) ----
  for (int i = tid; i < BT*HP; i += 256){ h0s[i] = (f16)0.f; h1s[i] = (f16)0.f; }
  for (int i = tid; i < 2*BT*XP; i += 256) xs[i] = (f16)0.f;
  __syncthreads();

  // ---- load weight B-fragments into registers (once) ----
  f16x8 Bhh0v[4][2], Bih1v[4][2], Bhh1v[4][2], Bih0v[4];
  float b0g[4], b1g[4];
  for (int g = 0; g < 4; ++g){
    const int n = 64*g + 16*w + c;
    for (int kt = 0; kt < 2; ++kt){
      const long off = (long)n*64 + kt*32 + q*8;
      for (int j = 0; j < 8; ++j){
        Bhh0v[g][kt][j] = (f16)ldv<BF16>(Whh0, off + j);
        Bih1v[g][kt][j] = (f16)ldv<BF16>(Wih1, off + j);
        Bhh1v[g][kt][j] = (f16)ldv<BF16>(Whh1, off + j);
      }
    }
    f16x8 bi = {};                       // zero-filled: k>=9 contributes 0
    if (q == 0){ for (int j = 0; j < 8; ++j) bi[j] = (f16)ldv<BF16>(Wih0, (long)n*9 + j); }
    else if (q == 1){ bi[0] = (f16)ldv<BF16>(Wih0, (long)n*9 + 8); }
    Bih0v[g] = bi;
    b0g[g] = ldv<BF16>(bih0, n) + ldv<BF16>(bhh0, n);
    b1g[g] = ldv<BF16>(bih1, n) + ldv<BF16>(bhh1, n);
  }

  // ---- x staging bookkeeping (all /9 hoisted out of the T-loop) ----
  int  xs_off[3]; long xg[3]; bool xv[3];
  for (int it = 0; it < 3; ++it){
    int e = tid + 256*it;
    xv[it] = (e < BT*Ii);
    int s = e / 9, i = e - s*9;
    if (!xv[it]){ s = 0; i = 0; }
    xs_off[it] = s*XP + i;
    xg[it] = (base + s)*(long)(Tt*Ii) + i;   // index of x[s][0][i]
  }
  // stage t=0 into xs buf 0; advance indices to t=1
  for (int it = 0; it < 3; ++it){
    if (xv[it]) xs[xs_off[it]] = (f16)ldv<BF16>(x, xg[it]);
    xg[it] += Ii;
  }

  float c0[4][4] = {};   // cell state L0: sample mt*16+4q+r, unit 16w+c
  float c1[4][4] = {};
  float hreg[4][4];      // final-step h1 (fp32) kept in regs until after last barrier
  float xpv[3];
  __syncthreads();

  for (int t = 0; t < Tt; ++t){
    const int rb = t & 1, wb = rb ^ 1;
    f16* h0r = h0s + rb*BT*HP; f16* h0w = h0s + wb*BT*HP;
    f16* h1r = h1s + rb*BT*HP; f16* h1w = h1s + wb*BT*HP;
    f16* xr  = xs  + rb*BT*XP; f16* xw  = xs  + wb*BT*XP;

    // prefetch x(t+1) into regs (hide HBM latency behind MFMA)
    const bool pf = (t + 1 < Tt);
    if (pf){
      for (int it = 0; it < 3; ++it){
        if (xv[it]) xpv[it] = ldv<BF16>(x, xg[it]);
        xg[it] += Ii;
      }
    }

    // ---- Phase A: layer0 gates = h0 @ Whh0^T + xpad @ Wih0^T + b0 ----
    f16x8 ah[4][2], ax[4];
    for (int mt = 0; mt < 4; ++mt){
      const f16* hp = &h0r[(mt*16 + c)*HP];
      ah[mt][0] = ld8lds(hp + q*8);
      ah[mt][1] = ld8lds(hp + 32 + q*8);
      f16x8 a = {};
      if (q < 2) a = ld8lds(&xr[(mt*16 + c)*XP + q*8]);  // k>=16 lanes supply zeros
      ax[mt] = a;
    }
    f32x4 acc[4][4];
    for (int mt = 0; mt < 4; ++mt)
      for (int g = 0; g < 4; ++g){
        f32x4 a = { b0g[g], b0g[g], b0g[g], b0g[g] };
        a = __builtin_amdgcn_mfma_f32_16x16x32_f16(ah[mt][0], Bhh0v[g][0], a, 0,0,0);
        a = __builtin_amdgcn_mfma_f32_16x16x32_f16(ah[mt][1], Bhh0v[g][1], a, 0,0,0);
        a = __builtin_amdgcn_mfma_f32_16x16x32_f16(ax[mt],    Bih0v[g],    a, 0,0,0);
        acc[mt][g] = a;
      }

    // ---- Phase B: layer0 cell update, h0_new -> LDS ----
    for (int mt = 0; mt < 4; ++mt)
      for (int r = 0; r < 4; ++r){
        float ig = sigm(acc[mt][0][r]);
        float fg = sigm(acc[mt][1][r]);
        float gg = tanh_(acc[mt][2][r]);
        float og = sigm(acc[mt][3][r]);
        float cn = __builtin_fmaf(fg, c0[mt][r], ig*gg);
        c0[mt][r] = cn;
        h0w[(mt*16 + 4*q + r)*HP + 16*w + c] = (f16)(og*tanh_(cn));
      }
    __syncthreads();

    // ---- Phase C: layer1 gates = h0_new @ Wih1^T + h1 @ Whh1^T + b1 ----
    f16x8 a0[4][2], a1[4][2];
    for (int mt = 0; mt < 4; ++mt){
      const f16* p0 = &h0w[(mt*16 + c)*HP];
      a0[mt][0] = ld8lds(p0 + q*8);
      a0[mt][1] = ld8lds(p0 + 32 + q*8);
      const f16* p1 = &h1r[(mt*16 + c)*HP];
      a1[mt][0] = ld8lds(p1 + q*8);
      a1[mt][1] = ld8lds(p1 + 32 + q*8);
    }
    for (int mt = 0; mt < 4; ++mt)
      for (int g = 0; g < 4; ++g){
        f32x4 a = { b1g[g], b1g[g], b1g[g], b1g[g] };
        a = __builtin_amdgcn_mfma_f32_16x16x32_f16(a0[mt][0], Bih1v[g][0], a, 0,0,0);
        a = __builtin_amdgcn_mfma_f32_16x16x32_f16(a0[mt][1], Bih1v[g][1], a, 0,0,0);
        a = __builtin_amdgcn_mfma_f32_16x16x32_f16(a1[mt][0], Bhh1v[g][0], a, 0,0,0);
        a = __builtin_amdgcn_mfma_f32_16x16x32_f16(a1[mt][1], Bhh1v[g][1], a, 0,0,0);
        acc[mt][g] = a;
      }

    // ---- Phase D: layer1 cell update, h1_new -> LDS ----
    for (int mt = 0; mt < 4; ++mt)
      for (int r = 0; r < 4; ++r){
        float ig = sigm(acc[mt][0][r]);
        float fg = sigm(acc[mt][1][r]);
        float gg = tanh_(acc[mt][2][r]);
        float og = sigm(acc[mt][3][r]);
        float cn = __builtin_fmaf(fg, c1[mt][r], ig*gg);
        c1[mt][r] = cn;
        float hh = og*tanh_(cn);
        hreg[mt][r] = hh;                 // only final step's value survives the loop
        h1w[(mt*16 + 4*q + r)*HP + 16*w + c] = (f16)hh;
      }
    if (pf){
      for (int it = 0; it < 3; ++it)
        if (xv[it]) xw[xs_off[it]] = (f16)xpv[it];
    }
    __syncthreads();
  }

  // ---- LayerNorm over final h1 (fp32). h0s/h1s are dead now -> alias scratch. ----
  float* hfin = (float*)h0s;            // BT x (Hh+1) fp32 = 16640 B <= 17408 B
  float* mus  = (float*)h1s;
  float* rss  = mus + BT;
  for (int mt = 0; mt < 4; ++mt)
    for (int r = 0; r < 4; ++r)
      hfin[(mt*16 + 4*q + r)*(Hh+1) + 16*w + c] = hreg[mt][r];
  __syncthreads();

  if (tid < BT){
    float s = 0.f, s2 = 0.f;
    for (int u = 0; u < Hh; ++u){ float v = hfin[tid*(Hh+1) + u]; s += v; s2 += v*v; }
    float m   = s  * (1.0f/Hh);
    float var = s2 * (1.0f/Hh) - m*m;     // biased var, matches jnp.var
    mus[tid] = m;
    rss[tid] = rsqrtf(var + 1e-5f);
  }
  __syncthreads();
  for (int itx = 0; itx < (BT*Hh)/256; ++itx){
    int idx = itx*256 + tid;
    int s = idx >> 6, u = idx & 63;
    float v = (hfin[s*(Hh+1) + u] - mus[s]) * rss[s];
    v = __builtin_fmaf(v, ldv<BF16>(gmma, u), ldv<BF16>(beta, u));
    long o = base*Hh + idx;
    if constexpr (BF16) ((__hip_bfloat16*)out)[o] = __float2bfloat16(v);
    else                ((float*)out)[o] = v;
  }
}

// (256,2): VGPR cap 256 -> no spill (the (256,3)/170-cap variant spilled weights
// to scratch: VGPR 84, 4 GB HBM spill traffic, 1340 us). Weight-resident design
// needs ~170 VGPR.
__global__ __launch_bounds__(256, 2) void lstm_fused(
    const void* __restrict__ x,
    const void* __restrict__ Wih0, const void* __restrict__ Whh0,
    const void* __restrict__ bih0, const void* __restrict__ bhh0,
    const void* __restrict__ Wih1, const void* __restrict__ Whh1,
    const void* __restrict__ bih1, const void* __restrict__ bhh1,
    const void* __restrict__ gmma, const void* __restrict__ beta,
    void* __restrict__ out, const int* __restrict__ flag)
{
  __shared__ __align__(16) f16 h0s[2*BT*HP];   // 17408 B (reused as fp32 hfin after loop)
  __shared__ __align__(16) f16 h1s[2*BT*HP];   // 17408 B (reused as mus/rss after loop)
  __shared__ __align__(16) f16 xs[2*BT*XP];    //  5120 B        -> total ~40 KB

  if (*flag)
    lstm_body<true >(x, Wih0, Whh0, bih0, bhh0, Wih1, Whh1, bih1, bhh1, gmma, beta,
                     out, h0s, h1s, xs);
  else
    lstm_body<false>(x, Wih0, Whh0, bih0, bhh0, Wih1, Whh1, bih1, bhh1, gmma, beta,
                     out, h0s, h1s, xs);
}

extern "C" void kernel_launch(void* const* d_in, const int* in_sizes, int n_in,
                              void* d_out, int out_size, void* d_ws, size_t ws_size,
                              hipStream_t stream) {
  const int B = in_sizes[0] / (Tt * Ii);   // 65536
  int* flag = (int*)d_ws;
  hipLaunchKernelGGL(detect_dtype, dim3(1), dim3(64), 0, stream, d_in[0], flag);
  hipLaunchKernelGGL(lstm_fused, dim3(B / BT), dim3(256), 0, stream,
                     d_in[0], d_in[1], d_in[2], d_in[3], d_in[4], d_in[5], d_in[6],
                     d_in[7], d_in[8], d_in[9], d_in[10], d_out, (const int*)flag);
}

// Round 5
// 457.629 us; speedup vs baseline: 2.9286x; 1.3980x over previous
//
#include <hip/hip_runtime.h>
#include <hip/hip_bf16.h>
#include <cstdint>

typedef _Float16 f16;
typedef f16 f16x4 __attribute__((ext_vector_type(4)));
typedef f16 f16x8 __attribute__((ext_vector_type(8)));
typedef float f32x4 __attribute__((ext_vector_type(4)));

static constexpr int Hh = 64;   // hidden
static constexpr int Tt = 30;   // seq len
static constexpr int Ii = 9;    // input features
static constexpr int BT = 64;   // batch tile per block
static constexpr int HP = 68;   // padded h-row stride (halves)
static constexpr int XP = 20;   // padded x-row stride (halves)
static constexpr int CS = 68;   // c1 LDS row stride (floats): bank = 4*row+col -> 2-way max (free)

__device__ __forceinline__ float bf2f(unsigned short u){
  return __uint_as_float(((unsigned int)u) << 16);
}
// fast activations: v_rcp_f32 (~1 ulp) instead of IEEE divide
__device__ __forceinline__ float sigm(float x){
  float e = __expf(-x);
  return __builtin_amdgcn_rcpf(1.0f + e);     // x->-inf: e=inf -> rcp(inf)=0 (no NaN)
}
__device__ __forceinline__ float tanh_(float x){
  float e = __expf(-2.0f*x);                  // saturates cleanly at +-1
  return __builtin_fmaf(2.0f, __builtin_amdgcn_rcpf(1.0f + e), -1.0f);
}

template<bool BF16>
__device__ __forceinline__ float ldv(const void* p, long i){
  if constexpr (BF16) return bf2f(((const unsigned short*)p)[i]);
  else                return ((const float*)p)[i];
}

__device__ __forceinline__ f16x8 ld8lds(const f16* p){
  f16x4 lo = *(const f16x4*)p;        // ds_read_b64
  f16x4 hi = *(const f16x4*)(p + 4);  // ds_read_b64
  f16x8 r;
  r[0]=lo[0]; r[1]=lo[1]; r[2]=lo[2]; r[3]=lo[3];
  r[4]=hi[0]; r[5]=hi[1]; r[6]=hi[2]; r[7]=hi[3];
  return r;
}

// bf16 data reinterpreted as fp32 would show huge/NaN exponents
__global__ void detect_dtype(const void* x, int* flag){
  if (threadIdx.x == 0 && blockIdx.x == 0){
    const float* f = (const float*)x;
    int big = 0;
    for (int i = 0; i < 64; ++i){
      float v = f[i];
      if (!(fabsf(v) < 1e10f)) big = 1;
    }
    *flag = big;
  }
}

// MFMA 16x16x32 f16 mapping:
//   A: m = lane&15, k = (lane>>4)*8 + j
//   B: n = lane&15, k = (lane>>4)*8 + j  (= row n of W[256][K], contiguous k)
//   C/D: n = lane&15, m = (lane>>4)*4 + reg
//
// Wave specialization: waves 0-3 = layer0 at step s; waves 4-7 = layer1 at
// step s-1 (1-step skew). h0[t] lands in buf (t+1)&1; layer1 reads h0 buf s&1.
// h1: read buf (s+1)&1, write buf s&1. One barrier per iteration, 31 iters.
template<bool BF16>
__device__ void lstm_body(const void* __restrict__ x,
                          const void* __restrict__ Wih0, const void* __restrict__ Whh0,
                          const void* __restrict__ bih0, const void* __restrict__ bhh0,
                          const void* __restrict__ Wih1, const void* __restrict__ Whh1,
                          const void* __restrict__ bih1, const void* __restrict__ bhh1,
                          const void* __restrict__ gmma, const void* __restrict__ beta,
                          void* __restrict__ out,
                          f16* h0s, f16* h1s, f16* xs, float* c1l)
{
  const int tid  = threadIdx.x;
  const int w8   = tid >> 6;       // wave 0..7
  const int lane = tid & 63;
  const int c    = lane & 15;
  const int q    = lane >> 4;
  const int lay  = w8 >> 2;        // 0: layer0 waves, 1: layer1 waves
  const int w    = w8 & 3;         // wave-within-layer: owns units 16w..16w+15
  const long base = (long)blockIdx.x * BT;

  // ---- zero-init: h0 buf0, h1 buf0, xs both bufs (incl pads), c1 state ----
  for (int i = tid; i < BT*HP; i += 512){ h0s[i] = (f16)0.f; h1s[i] = (f16)0.f; }
  for (int i = tid; i < 2*BT*XP; i += 512) xs[i] = (f16)0.f;
  for (int i = tid; i < BT*CS;   i += 512) c1l[i] = 0.f;
  __syncthreads();

  // ---- stage x[t=0] (layer0 threads = tid<256) ----
  if (lay == 0){
    for (int e = tid; e < BT*Ii; e += 256){
      int s = e / 9, i = e - s*9;
      xs[s*XP + i] = (f16)ldv<BF16>(x, (base + s)*(long)(Tt*Ii) + i);
    }
  }
  __syncthreads();

  if (lay == 0){
    // ================= LAYER 0 waves =================
    f16x8 W0[4][2];  f16x8 Wx[4];  float bg[4];
    for (int g = 0; g < 4; ++g){
      const int n = 64*g + 16*w + c;
      for (int kt = 0; kt < 2; ++kt){
        const long off = (long)n*64 + kt*32 + q*8;
        for (int j = 0; j < 8; ++j) W0[g][kt][j] = (f16)ldv<BF16>(Whh0, off + j);
      }
      f16x8 bi = {};
      if (q == 0){ for (int j = 0; j < 8; ++j) bi[j] = (f16)ldv<BF16>(Wih0, (long)n*9 + j); }
      else if (q == 1){ bi[0] = (f16)ldv<BF16>(Wih0, (long)n*9 + 8); }
      Wx[g] = bi;
      bg[g] = ldv<BF16>(bih0, n) + ldv<BF16>(bhh0, n);
    }
    // x staging bookkeeping (hoisted /9)
    int xs_off[3]; int xg[3]; bool xv[3];
    for (int it = 0; it < 3; ++it){
      int e = tid + 256*it;
      xv[it] = (e < BT*Ii);
      int s = e / 9, i = e - s*9;
      if (!xv[it]){ s = 0; i = 0; }
      xs_off[it] = s*XP + i;
      xg[it] = s*(Tt*Ii) + Ii + i;       // x[s][t=1][i], relative to block base
    }
    const void* xb = BF16 ? (const void*)((const unsigned short*)x + base*(Tt*Ii))
                          : (const void*)((const float*)x + base*(Tt*Ii));
    float c0[4][4] = {};
    float xpv[3];

    for (int s = 0; s <= Tt; ++s){
      if (s < Tt){
        const int t = s, rb = t & 1, wb = rb ^ 1;
        const f16* h0r = h0s + rb*BT*HP;
        f16*       h0w = h0s + wb*BT*HP;
        const f16* xr  = xs  + rb*BT*XP;
        f16*       xw  = xs  + wb*BT*XP;
        const bool pf = (t + 1 < Tt);
        if (pf){
          for (int it = 0; it < 3; ++it){
            if (xv[it]) xpv[it] = ldv<BF16>(xb, xg[it]);
            xg[it] += Ii;
          }
        }
        for (int mt = 0; mt < 4; ++mt){
          const f16* hp = &h0r[(mt*16 + c)*HP];
          f16x8 ah0 = ld8lds(hp + q*8);
          f16x8 ah1 = ld8lds(hp + 32 + q*8);
          f16x8 ax = {};
          if (q < 2) ax = ld8lds(&xr[(mt*16 + c)*XP + q*8]);
          f32x4 acc[4];
          for (int g = 0; g < 4; ++g){
            f32x4 a = { bg[g], bg[g], bg[g], bg[g] };
            a = __builtin_amdgcn_mfma_f32_16x16x32_f16(ah0, W0[g][0], a, 0,0,0);
            a = __builtin_amdgcn_mfma_f32_16x16x32_f16(ah1, W0[g][1], a, 0,0,0);
            a = __builtin_amdgcn_mfma_f32_16x16x32_f16(ax,  Wx[g],    a, 0,0,0);
            acc[g] = a;
          }
          for (int r = 0; r < 4; ++r){
            float ig = sigm(acc[0][r]);
            float fg = sigm(acc[1][r]);
            float gg = tanh_(acc[2][r]);
            float og = sigm(acc[3][r]);
            float cn = __builtin_fmaf(fg, c0[mt][r], ig*gg);
            c0[mt][r] = cn;
            h0w[(mt*16 + 4*q + r)*HP + 16*w + c] = (f16)(og*tanh_(cn));
          }
        }
        if (pf){
          for (int it = 0; it < 3; ++it)
            if (xv[it]) xw[xs_off[it]] = (f16)xpv[it];
        }
      }
      __syncthreads();
    }
  } else {
    // ================= LAYER 1 waves =================
    f16x8 W1a[4][2], W1b[4][2];  float bg[4];
    for (int g = 0; g < 4; ++g){
      const int n = 64*g + 16*w + c;
      for (int kt = 0; kt < 2; ++kt){
        const long off = (long)n*64 + kt*32 + q*8;
        for (int j = 0; j < 8; ++j){
          W1a[g][kt][j] = (f16)ldv<BF16>(Wih1, off + j);
          W1b[g][kt][j] = (f16)ldv<BF16>(Whh1, off + j);
        }
      }
      bg[g] = ldv<BF16>(bih1, n) + ldv<BF16>(bhh1, n);
    }

    for (int s = 0; s <= Tt; ++s){
      if (s >= 1){
        const f16* h0r = h0s + (s & 1)*BT*HP;        // h0[s-1]
        const f16* h1r = h1s + ((s + 1) & 1)*BT*HP;  // h1[s-2]
        f16*       h1w = h1s + (s & 1)*BT*HP;        // h1[s-1]
        for (int mt = 0; mt < 4; ++mt){
          const f16* p0 = &h0r[(mt*16 + c)*HP];
          f16x8 a00 = ld8lds(p0 + q*8);
          f16x8 a01 = ld8lds(p0 + 32 + q*8);
          const f16* p1 = &h1r[(mt*16 + c)*HP];
          f16x8 a10 = ld8lds(p1 + q*8);
          f16x8 a11 = ld8lds(p1 + 32 + q*8);
          f32x4 acc[4];
          for (int g = 0; g < 4; ++g){
            f32x4 a = { bg[g], bg[g], bg[g], bg[g] };
            a = __builtin_amdgcn_mfma_f32_16x16x32_f16(a00, W1a[g][0], a, 0,0,0);
            a = __builtin_amdgcn_mfma_f32_16x16x32_f16(a01, W1a[g][1], a, 0,0,0);
            a = __builtin_amdgcn_mfma_f32_16x16x32_f16(a10, W1b[g][0], a, 0,0,0);
            a = __builtin_amdgcn_mfma_f32_16x16x32_f16(a11, W1b[g][1], a, 0,0,0);
            acc[g] = a;
          }
          for (int r = 0; r < 4; ++r){
            const int ci = (mt*16 + 4*q + r)*CS + 16*w + c;
            float ig = sigm(acc[0][r]);
            float fg = sigm(acc[1][r]);
            float gg = tanh_(acc[2][r]);
            float og = sigm(acc[3][r]);
            float cn = __builtin_fmaf(fg, c1l[ci], ig*gg);
            c1l[ci] = cn;
            h1w[(mt*16 + 4*q + r)*HP + 16*w + c] = (f16)(og*tanh_(cn));
          }
        }
      }
      __syncthreads();
    }
  }

  // ---- LayerNorm over final h1 (in h1s buf (Tt&1)=0, f16). xs is dead -> scratch. ----
  const f16* hf = h1s;                 // buf0
  float* mus = (float*)xs;
  float* rss = mus + BT;
  if (tid < BT){
    float sm = 0.f, s2 = 0.f;
    for (int u = 0; u < Hh; ++u){ float v = (float)hf[tid*HP + u]; sm += v; s2 += v*v; }
    float m   = sm * (1.0f/Hh);
    float var = s2 * (1.0f/Hh) - m*m;  // biased var, matches jnp.var
    mus[tid] = m;
    rss[tid] = rsqrtf(var + 1e-5f);
  }
  __syncthreads();
  for (int it = 0; it < (BT*Hh)/512; ++it){
    int idx = it*512 + tid;
    int sIdx = idx >> 6, u = idx & 63;
    float v = ((float)hf[sIdx*HP + u] - mus[sIdx]) * rss[sIdx];
    v = __builtin_fmaf(v, ldv<BF16>(gmma, u), ldv<BF16>(beta, u));
    long o = base*Hh + idx;
    if constexpr (BF16) ((__hip_bfloat16*)out)[o] = __float2bfloat16(v);
    else                ((float*)out)[o] = v;
  }
}

// (512,4): cap 128 VGPR -> 4 waves/SIMD, 2 blocks/CU. Per-layer wave
// specialization keeps per-wave weight regs at 48/64 so 128 suffices.
__global__ __launch_bounds__(512, 4) void lstm_fused(
    const void* __restrict__ x,
    const void* __restrict__ Wih0, const void* __restrict__ Whh0,
    const void* __restrict__ bih0, const void* __restrict__ bhh0,
    const void* __restrict__ Wih1, const void* __restrict__ Whh1,
    const void* __restrict__ bih1, const void* __restrict__ bhh1,
    const void* __restrict__ gmma, const void* __restrict__ beta,
    void* __restrict__ out, const int* __restrict__ flag)
{
  __shared__ __align__(16) f16 h0s[2*BT*HP];    // 17408 B
  __shared__ __align__(16) f16 h1s[2*BT*HP];    // 17408 B
  __shared__ __align__(16) f16 xs[2*BT*XP];     //  5120 B (LN scratch after loop)
  __shared__ __align__(16) float c1l[BT*CS];    // 17408 B layer1 cell state
                                                // total 57344 B -> 2 blocks/CU
  if (*flag)
    lstm_body<true >(x, Wih0, Whh0, bih0, bhh0, Wih1, Whh1, bih1, bhh1, gmma, beta,
                     out, h0s, h1s, xs, c1l);
  else
    lstm_body<false>(x, Wih0, Whh0, bih0, bhh0, Wih1, Whh1, bih1, bhh1, gmma, beta,
                     out, h0s, h1s, xs, c1l);
}

extern "C" void kernel_launch(void* const* d_in, const int* in_sizes, int n_in,
                              void* d_out, int out_size, void* d_ws, size_t ws_size,
                              hipStream_t stream) {
  const int B = in_sizes[0] / (Tt * Ii);   // 65536
  int* flag = (int*)d_ws;
  hipLaunchKernelGGL(detect_dtype, dim3(1), dim3(64), 0, stream, d_in[0], flag);
  hipLaunchKernelGGL(lstm_fused, dim3(B / BT), dim3(512), 0, stream,
                     d_in[0], d_in[1], d_in[2], d_in[3], d_in[4], d_in[5], d_in[6],
                     d_in[7], d_in[8], d_in[9], d_in[10], d_out, (const int*)flag);
}

// Round 8
// 401.052 us; speedup vs baseline: 3.3418x; 1.1411x over previous
//
#include <hip/hip_runtime.h>
#include <hip/hip_bf16.h>
#include <cstdint>

typedef _Float16 f16;
typedef f16 f16x8 __attribute__((ext_vector_type(8)));
typedef float f32x4 __attribute__((ext_vector_type(4)));

static constexpr int Hh = 64;   // hidden
static constexpr int Tt = 30;   // seq len
static constexpr int Ii = 9;    // input features
static constexpr int BT = 64;   // batch tile per block
static constexpr int HP = 72;   // h-row stride (halves): 144 B rows -> A-frags 16B-aligned (b128)
static constexpr int XP = 24;   // x-row stride (halves): 48 B rows, 16B-aligned
static constexpr int CS = 68;   // c1 LDS stride (floats): <=2-way bank aliasing (free)

static constexpr float L2E = 1.4426950408889634f;

__device__ __forceinline__ float bf2f(unsigned short u){
  return __uint_as_float(((unsigned int)u) << 16);
}

template<bool BF16>
__device__ __forceinline__ float ldv(const void* p, long i){
  if constexpr (BF16) return bf2f(((const unsigned short*)p)[i]);
  else                return ((const float*)p)[i];
}

// Gates arrive pre-scaled by log2e (i,f,o) and 2*log2e (g); cell state kept as
// chat = -2*log2e*c. Per update: 4 v_exp2 + 4 v_rcp + ~6 full-rate ops.
__device__ __forceinline__ float cell_update(float ai, float af, float ag, float ao, float& chat){
  float ri = __builtin_amdgcn_rcpf(1.0f + __builtin_amdgcn_exp2f(-ai));  // sigmoid(i)
  float rf = __builtin_amdgcn_rcpf(1.0f + __builtin_amdgcn_exp2f(-af));  // sigmoid(f)
  float rg = __builtin_amdgcn_rcpf(1.0f + __builtin_amdgcn_exp2f(-ag));  // (tanh(g)+1)/2
  float ro = __builtin_amdgcn_rcpf(1.0f + __builtin_amdgcn_exp2f(-ao));  // sigmoid(o)
  float gs = __builtin_fmaf(rg, -4.0f*L2E, 2.0f*L2E);   // = -2*log2e * tanh(g)
  chat = __builtin_fmaf(rf, chat, ri*gs);               // chat' = f*chat + i*gs
  float rt = __builtin_amdgcn_rcpf(1.0f + __builtin_amdgcn_exp2f(chat)); // (tanh(c)+1)/2
  float o2 = ro + ro;
  return __builtin_fmaf(o2, rt, -ro);                   // h = o * tanh(c)
}

// bf16 data reinterpreted as fp32 shows huge/NaN exponents
__global__ void detect_dtype(const void* x, int* flag){
  if (threadIdx.x == 0 && blockIdx.x == 0){
    const float* f = (const float*)x;
    int big = 0;
    for (int i = 0; i < 64; ++i){
      float v = f[i];
      if (!(fabsf(v) < 1e10f)) big = 1;
    }
    *flag = big;
  }
}

// MFMA 16x16x32 f16 mapping:
//   A: m = lane&15, k = (lane>>4)*8 + j
//   B: n = lane&15, k = (lane>>4)*8 + j  (= row n of W[256][K], contiguous k)
//   C/D: n = lane&15, m = (lane>>4)*4 + reg
// Wave specialization: waves 0-3 = layer0 step s; waves 4-7 = layer1 step s-1.
// IDENTICAL barrier skeleton in both branches (R5-proven): s=0..Tt, guarded
// body, one barrier per iteration. No unroll pragma on the barrier loop.
template<bool BF16>
__device__ void lstm_body(const void* __restrict__ x,
                          const void* __restrict__ Wih0, const void* __restrict__ Whh0,
                          const void* __restrict__ bih0, const void* __restrict__ bhh0,
                          const void* __restrict__ Wih1, const void* __restrict__ Whh1,
                          const void* __restrict__ bih1, const void* __restrict__ bhh1,
                          const void* __restrict__ gmma, const void* __restrict__ beta,
                          void* __restrict__ out,
                          f16* h0s, f16* h1s, f16* xs, float* c1l)
{
  const int tid  = threadIdx.x;
  const int w8   = tid >> 6;
  const int lane = tid & 63;
  const int c    = lane & 15;
  const int q    = lane >> 4;
  const int lay  = w8 >> 2;
  const int w    = w8 & 3;
  const long base = (long)blockIdx.x * BT;
  const float gsc[4] = { L2E, L2E, 2.0f*L2E, L2E };   // per-gate exp2 pre-scale

  // ---- zero-init: h0/h1 buf0, xs both bufs (incl pads), c1 state ----
  for (int i = tid; i < BT*HP; i += 512){ h0s[i] = (f16)0.f; h1s[i] = (f16)0.f; }
  for (int i = tid; i < 2*BT*XP; i += 512) xs[i] = (f16)0.f;
  for (int i = tid; i < BT*CS;   i += 512) c1l[i] = 0.f;
  __syncthreads();

  // ---- stage x[t=0] ----
  if (lay == 0){
    for (int e = tid; e < BT*Ii; e += 256){
      int s = e / 9, i = e - s*9;
      xs[s*XP + i] = (f16)ldv<BF16>(x, (base + s)*(long)(Tt*Ii) + i);
    }
  }
  __syncthreads();

  if (lay == 0){
    // ================= LAYER 0 waves =================
    f16x8 W0[4][2];  f16x8 Wx[4];  f32x4 bsp[4];
    for (int g = 0; g < 4; ++g){
      const int n = 64*g + 16*w + c;
      const float sc = gsc[g];
      for (int kt = 0; kt < 2; ++kt){
        const long off = (long)n*64 + kt*32 + q*8;
        for (int j = 0; j < 8; ++j) W0[g][kt][j] = (f16)(sc * ldv<BF16>(Whh0, off + j));
      }
      f16x8 bi = {};
      if (q == 0){ for (int j = 0; j < 8; ++j) bi[j] = (f16)(sc * ldv<BF16>(Wih0, (long)n*9 + j)); }
      else if (q == 1){ bi[0] = (f16)(sc * ldv<BF16>(Wih0, (long)n*9 + 8)); }
      Wx[g] = bi;
      float bb = sc * (ldv<BF16>(bih0, n) + ldv<BF16>(bhh0, n));
      bsp[g] = (f32x4){ bb, bb, bb, bb };
    }
    // x staging bookkeeping (hoisted /9)
    int xs_off[3]; int xg[3]; bool xv[3];
    for (int it = 0; it < 3; ++it){
      int e = tid + 256*it;
      xv[it] = (e < BT*Ii);
      int s = e / 9, i = e - s*9;
      if (!xv[it]){ s = 0; i = 0; }
      xs_off[it] = s*XP + i;
      xg[it] = s*(Tt*Ii) + Ii + i;
    }
    const void* xb = BF16 ? (const void*)((const unsigned short*)x + base*(Tt*Ii))
                          : (const void*)((const float*)x + base*(Tt*Ii));
    float c0[4][4] = {};   // chat-domain cell state
    float xpv[3];
    const int aoff = c*HP + q*8;
    const int xoff = c*XP + q*8;
    const int woff = 4*q*HP + 16*w + c;

    for (int s = 0; s <= Tt; ++s){
      if (s < Tt){
        const int rb = s & 1, wb = rb ^ 1;
        const f16* ha = h0s + rb*(BT*HP) + aoff;
        const f16* xa = xs  + rb*(BT*XP) + xoff;
        f16*       hw = h0s + wb*(BT*HP) + woff;
        f16*       xw = xs  + wb*(BT*XP);
        const bool pf = (s + 1 < Tt);
        if (pf){
          for (int it = 0; it < 3; ++it){
            if (xv[it]) xpv[it] = ldv<BF16>(xb, xg[it]);
            xg[it] += Ii;
          }
        }
#pragma unroll
        for (int mt = 0; mt < 4; ++mt){
          f16x8 ah0 = *(const f16x8*)(ha + mt*16*HP);        // ds_read_b128
          f16x8 ah1 = *(const f16x8*)(ha + mt*16*HP + 32);
          f16x8 ax = {};
          if (q < 2) ax = *(const f16x8*)(xa + mt*16*XP);
          f32x4 acc[4];
#pragma unroll
          for (int g = 0; g < 4; ++g){
            f32x4 a = __builtin_amdgcn_mfma_f32_16x16x32_f16(ah0, W0[g][0], bsp[g], 0,0,0);
            a = __builtin_amdgcn_mfma_f32_16x16x32_f16(ah1, W0[g][1], a, 0,0,0);
            a = __builtin_amdgcn_mfma_f32_16x16x32_f16(ax,  Wx[g],    a, 0,0,0);
            acc[g] = a;
          }
#pragma unroll
          for (int r = 0; r < 4; ++r){
            float h = cell_update(acc[0][r], acc[1][r], acc[2][r], acc[3][r], c0[mt][r]);
            hw[(mt*16 + r)*HP] = (f16)h;
          }
        }
        if (pf){
          for (int it = 0; it < 3; ++it)
            if (xv[it]) xw[xs_off[it]] = (f16)xpv[it];
        }
      }
      __syncthreads();
    }
  } else {
    // ================= LAYER 1 waves =================
    f16x8 W1a[4][2], W1b[4][2];  f32x4 bsp[4];
    for (int g = 0; g < 4; ++g){
      const int n = 64*g + 16*w + c;
      const float sc = gsc[g];
      for (int kt = 0; kt < 2; ++kt){
        const long off = (long)n*64 + kt*32 + q*8;
        for (int j = 0; j < 8; ++j){
          W1a[g][kt][j] = (f16)(sc * ldv<BF16>(Wih1, off + j));
          W1b[g][kt][j] = (f16)(sc * ldv<BF16>(Whh1, off + j));
        }
      }
      float bb = sc * (ldv<BF16>(bih1, n) + ldv<BF16>(bhh1, n));
      bsp[g] = (f32x4){ bb, bb, bb, bb };
    }
    const int aoff = c*HP + q*8;
    const int woff = 4*q*HP + 16*w + c;
    float* cb = c1l + 4*q*CS + 16*w + c;

    for (int s = 0; s <= Tt; ++s){
      if (s >= 1){
        const int p = s & 1;                           // h0[s-1] is in buf (s&1)
        const f16* a0 = h0s + p*(BT*HP) + aoff;        // h0[s-1]
        const f16* a1 = h1s + (p ^ 1)*(BT*HP) + aoff;  // h1[s-2]
        f16*       hw = h1s + p*(BT*HP) + woff;        // h1[s-1]
#pragma unroll
        for (int mt = 0; mt < 4; ++mt){
          f16x8 a00 = *(const f16x8*)(a0 + mt*16*HP);
          f16x8 a01 = *(const f16x8*)(a0 + mt*16*HP + 32);
          f16x8 a10 = *(const f16x8*)(a1 + mt*16*HP);
          f16x8 a11 = *(const f16x8*)(a1 + mt*16*HP + 32);
          f32x4 acc[4];
#pragma unroll
          for (int g = 0; g < 4; ++g){
            f32x4 a = __builtin_amdgcn_mfma_f32_16x16x32_f16(a00, W1a[g][0], bsp[g], 0,0,0);
            a = __builtin_amdgcn_mfma_f32_16x16x32_f16(a01, W1a[g][1], a, 0,0,0);
            a = __builtin_amdgcn_mfma_f32_16x16x32_f16(a10, W1b[g][0], a, 0,0,0);
            a = __builtin_amdgcn_mfma_f32_16x16x32_f16(a11, W1b[g][1], a, 0,0,0);
            acc[g] = a;
          }
#pragma unroll
          for (int r = 0; r < 4; ++r){
            float ch = cb[(mt*16 + r)*CS];
            float h = cell_update(acc[0][r], acc[1][r], acc[2][r], acc[3][r], ch);
            cb[(mt*16 + r)*CS] = ch;
            hw[(mt*16 + r)*HP] = (f16)h;
          }
        }
      }
      __syncthreads();
    }
  }

  // ---- LayerNorm over final h1 (h1s buf (Tt&1)=0, f16). xs dead -> scratch. ----
  const f16* hf = h1s;
  float* mus = (float*)xs;
  float* rss = mus + BT;
  if (tid < BT){
    float sm = 0.f, s2 = 0.f;
    for (int u = 0; u < Hh; ++u){ float v = (float)hf[tid*HP + u]; sm += v; s2 += v*v; }
    float m   = sm * (1.0f/Hh);
    float var = s2 * (1.0f/Hh) - m*m;   // biased var, matches jnp.var
    mus[tid] = m;
    rss[tid] = rsqrtf(var + 1e-5f);
  }
  __syncthreads();
  for (int it = 0; it < (BT*Hh)/512; ++it){
    int idx = it*512 + tid;
    int sIdx = idx >> 6, u = idx & 63;
    float v = ((float)hf[sIdx*HP + u] - mus[sIdx]) * rss[sIdx];
    v = __builtin_fmaf(v, ldv<BF16>(gmma, u), ldv<BF16>(beta, u));
    long o = base*Hh + idx;
    if constexpr (BF16) ((__hip_bfloat16*)out)[o] = __float2bfloat16(v);
    else                ((float*)out)[o] = v;
  }
}

// (512,4): VGPR cap 128 -> 4 waves/SIMD, 2 blocks/CU (LDS ~59 KB).
__global__ __launch_bounds__(512, 4) void lstm_fused(
    const void* __restrict__ x,
    const void* __restrict__ Wih0, const void* __restrict__ Whh0,
    const void* __restrict__ bih0, const void* __restrict__ bhh0,
    const void* __restrict__ Wih1, const void* __restrict__ Whh1,
    const void* __restrict__ bih1, const void* __restrict__ bhh1,
    const void* __restrict__ gmma, const void* __restrict__ beta,
    void* __restrict__ out, const int* __restrict__ flag)
{
  __shared__ __align__(16) f16 h0s[2*BT*HP];    // 18432 B
  __shared__ __align__(16) f16 h1s[2*BT*HP];    // 18432 B
  __shared__ __align__(16) f16 xs[2*BT*XP];     //  6144 B (LN scratch after loop)
  __shared__ __align__(16) float c1l[BT*CS];    // 17408 B  -> total 60416 B
  if (*flag)
    lstm_body<true >(x, Wih0, Whh0, bih0, bhh0, Wih1, Whh1, bih1, bhh1, gmma, beta,
                     out, h0s, h1s, xs, c1l);
  else
    lstm_body<false>(x, Wih0, Whh0, bih0, bhh0, Wih1, Whh1, bih1, bhh1, gmma, beta,
                     out, h0s, h1s, xs, c1l);
}

extern "C" void kernel_launch(void* const* d_in, const int* in_sizes, int n_in,
                              void* d_out, int out_size, void* d_ws, size_t ws_size,
                              hipStream_t stream) {
  const int B = in_sizes[0] / (Tt * Ii);   // 65536
  int* flag = (int*)d_ws;
  hipLaunchKernelGGL(detect_dtype, dim3(1), dim3(64), 0, stream, d_in[0], flag);
  hipLaunchKernelGGL(lstm_fused, dim3(B / BT), dim3(512), 0, stream,
                     d_in[0], d_in[1], d_in[2], d_in[3], d_in[4], d_in[5], d_in[6],
                     d_in[7], d_in[8], d_in[9], d_in[10], d_out, (const int*)flag);
}